// Round 17
// baseline (274.367 us; speedup 1.0000x reference)
//
#include <hip/hip_runtime.h>
#include <hip/hip_bf16.h>

#define BB 16
#define CIN 256
#define DD 256
#define HH 96
#define NPIX 9216
#define HEADS 8
#define HD 32
#define MM 4

#define LBP 264   // padded lB row pitch (ushorts), 528 B, 16B-aligned
#define SWZ(n) ((((n) ^ ((n) >> 3)) & 7) << 3)

typedef short bf16x8 __attribute__((ext_vector_type(8)));
typedef float f32x4 __attribute__((ext_vector_type(4)));

__device__ __forceinline__ float b2f(unsigned u) {
    unsigned x = u << 16;
    return __builtin_bit_cast(float, x);
}
__device__ __forceinline__ ushort f2b(float f) {
    unsigned x = __builtin_bit_cast(unsigned, f);
    unsigned r = (x + 0x7FFF + ((x >> 16) & 1)) >> 16;  // RNE
    return (ushort)r;
}
__device__ __forceinline__ void unpack8(uint4 q, float* f) {
    f[0] = b2f(q.x & 0xffffu); f[1] = b2f(q.x >> 16);
    f[2] = b2f(q.y & 0xffffu); f[3] = b2f(q.y >> 16);
    f[4] = b2f(q.z & 0xffffu); f[5] = b2f(q.z >> 16);
    f[6] = b2f(q.w & 0xffffu); f[7] = b2f(q.w >> 16);
}
__device__ __forceinline__ void gload16(const ushort* g, ushort* l) {
    __builtin_amdgcn_global_load_lds(
        (const __attribute__((address_space(1))) unsigned int*)g,
        (__attribute__((address_space(3))) unsigned int*)l, 16, 0, 0);
}

// ---------------------------------------------------------------------------
// wprep: blocks 0..127: Wf,Wv f32 -> bf16 wb; blocks 128..159: GT + gb.
// ---------------------------------------------------------------------------
__global__ __launch_bounds__(256) void wprep_kernel(const float* __restrict__ Wf,
                                                    const float* __restrict__ Wv,
                                                    const float* __restrict__ bfp,
                                                    const float* __restrict__ centers,
                                                    ushort* __restrict__ wb,
                                                    float* __restrict__ GT,
                                                    float* __restrict__ gb) {
    __shared__ float cns[4][32];
    int t = threadIdx.x;
    if (blockIdx.x < 128) {
        int i = (blockIdx.x * 256 + t) * 4;
        float4 v;
        if (i < 65536) v = *(const float4*)(Wf + i);
        else v = *(const float4*)(Wv + (i - 65536));
        ushort4 o;
        o.x = f2b(v.x); o.y = f2b(v.y); o.z = f2b(v.z); o.w = f2b(v.w);
        *(ushort4*)(wb + i) = o;
        return;
    }
    if (t < 4) {
        float c[32]; float s = 0.f;
        for (int d = 0; d < 32; ++d) { c[d] = centers[t * 32 + d]; s += c[d] * c[d]; }
        float inv = 1.f / fmaxf(sqrtf(s), 1e-12f);
        for (int d = 0; d < 32; ++d) cns[t][d] = c[d] * inv;
    }
    __syncthreads();
    int i = (blockIdx.x - 128) * 256 + t;
    int c = i >> 5, em = i & 31;
    int e = em >> 2, m = em & 3;
    float s = 0.f;
#pragma unroll 8
    for (int d = 0; d < 32; ++d) s += cns[m][d] * Wf[(e * 32 + d) * 256 + c];
    GT[i] = s;
    if (blockIdx.x == 128 && t < 32) {
        int e2 = t >> 2, m2 = t & 3;
        float sb = 0.f;
        for (int d = 0; d < 32; ++d) sb += cns[m2][d] * bfp[e2 * 32 + d];
        gb[t] = sb;
    }
}

// ---------------------------------------------------------------------------
// gmap v5: em split by blockIdx.z (uniform -> s_load). 1 px/thread,
// 16 em/thread (acc=16 regs, no loop-distribution). Grid (36,16,2).
// ---------------------------------------------------------------------------
__global__ __launch_bounds__(256) void gmap_kernel(const float* __restrict__ x,
                                                   const float* __restrict__ GT,
                                                   const float* __restrict__ gb,
                                                   const float* __restrict__ alpha_p,
                                                   unsigned char* __restrict__ idxg,
                                                   float* __restrict__ zbest) {
    int b = blockIdx.y;
    int emh = blockIdx.z;                    // 0: em 0..15 (heads 0-3), 1: em 16..31
    int t = threadIdx.x;
    int n = blockIdx.x * 256 + t;
    float acc[16];
#pragma unroll
    for (int em = 0; em < 16; ++em) acc[em] = gb[emh * 16 + em];
    const float* xb = x + (size_t)b * CIN * NPIX + n;
    const float* gtb = GT + emh * 16;
#pragma unroll 8
    for (int c = 0; c < 256; ++c) {
        float xv = xb[(size_t)c * NPIX];
        const float* gr = gtb + c * 32;      // blockIdx-uniform -> s_load
#pragma unroll
        for (int em = 0; em < 16; ++em) acc[em] = fmaf(gr[em], xv, acc[em]);
    }
    float alpha = alpha_p[0];
#pragma unroll
    for (int h = 0; h < 4; ++h) {
        int e = emh * 4 + h;
        float z0 = alpha * acc[h * 4 + 0], z1 = alpha * acc[h * 4 + 1];
        float z2 = alpha * acc[h * 4 + 2], z3 = alpha * acc[h * 4 + 3];
        int bm = 0; float bz = z0;
        if (z1 > bz) { bz = z1; bm = 1; }
        if (z2 > bz) { bz = z2; bm = 2; }
        if (z3 > bz) { bz = z3; bm = 3; }
        size_t o = ((size_t)(b * 8 + e)) * NPIX + n;
        idxg[o] = (unsigned char)bm;
        zbest[o] = bz;
    }
}

// ---------------------------------------------------------------------------
// gemm_fvx v4: COALESCED x read (wave = 4 c-rows x 64 n contiguous) +
// in-register 4x4 shfl transpose + b64 LDS writes. lB rows padded to 264,
// SWZ(n) xor on both write and read. Same values/MFMA order as r13-r16 ->
// bitwise-identical fv. lB 33KB + lA 16KB = 50KB -> 3 blocks/CU. Grid (144,16).
// ---------------------------------------------------------------------------
__global__ __launch_bounds__(256, 3) void gemm_fvx(const ushort* __restrict__ wb,
                                                   const float* __restrict__ bfp,
                                                   const float* __restrict__ bvp,
                                                   const float* __restrict__ x,
                                                   ushort* __restrict__ fv) {
    __shared__ ushort lB[64 * LBP];   // 33,792 B
    __shared__ ushort lA[256 * 32];   // 16,384 B
    int nt = blockIdx.x, b = blockIdx.y;
    int t = threadIdx.x;
    int wave = t >> 6, lane = t & 63;
    int l15 = lane & 15, g8 = (lane >> 4) * 8, rg = lane >> 4;
    int n0 = nt * 64;

    // ---- B-stage: coalesced read + 4x4 lane-quad transpose + b64 write
    {
        int q = lane & 15, d = lane >> 4;
        int b0 = d & 1, b1 = d >> 1;
        for (int s = 0; s < 16; ++s) {
            int c0 = s * 16 + wave * 4;
            float4 v = *(const float4*)(x + ((size_t)(b * CIN + c0 + d)) * NPIX + n0 + q * 4);
            float a0 = v.x, a1 = v.y, a2 = v.z, a3 = v.w;
            // phase 1: xor 16 (d-bit0 <-> elem-bit0)
            float u0 = b0 ? a0 : a1;
            float r0 = __shfl_xor(u0, 16);
            float t0 = b0 ? r0 : a0;
            float t1 = b0 ? a1 : r0;
            float u1 = b0 ? a2 : a3;
            float r1 = __shfl_xor(u1, 16);
            float t2 = b0 ? r1 : a2;
            float t3 = b0 ? a3 : r1;
            // phase 2: xor 32 (d-bit1 <-> elem-bit1)
            float w0 = b1 ? t0 : t2;
            float s0_ = __shfl_xor(w0, 32);
            float A0 = b1 ? s0_ : t0;
            float A2 = b1 ? t2 : s0_;
            float w1 = b1 ? t1 : t3;
            float s1_ = __shfl_xor(w1, 32);
            float A1 = b1 ? s1_ : t1;
            float A3 = b1 ? t3 : s1_;
            // lane now holds n = q*4 + d with c-run c0..c0+3
            int nw = q * 4 + d;
            int cw = c0 ^ SWZ(nw);
            unsigned lo = (unsigned)f2b(A0) | ((unsigned)f2b(A1) << 16);
            unsigned hi = (unsigned)f2b(A2) | ((unsigned)f2b(A3) << 16);
            *(uint2*)(lB + (size_t)nw * LBP + cw) = make_uint2(lo, hi);
        }
    }
    __syncthreads();

    const ushort* aBase = wb + (t >> 2) * 256 + (t & 3) * 8;
    ushort* la0 = lA + wave * 512;    // HW adds lane*16B
#pragma unroll
    for (int g = 0; g < 2; ++g) {
        f32x4 acc[4][4] = {};
        const ushort* aSrc = aBase + (size_t)g * 65536;
        for (int kk = 0; kk < 8; ++kk) {
            int k0 = kk * 32;
            gload16(aSrc + k0, la0);
            gload16(aSrc + 64 * 256 + k0, la0 + 2048);
            gload16(aSrc + 128 * 256 + k0, la0 + 4096);
            gload16(aSrc + 192 * 256 + k0, la0 + 6144);
            __syncthreads();
            bf16x8 af[4], bb[4];
#pragma unroll
            for (int i = 0; i < 4; ++i)
                af[i] = *(const bf16x8*)(lA + (wave * 64 + i * 16 + l15) * 32 + g8);
#pragma unroll
            for (int j = 0; j < 4; ++j) {
                int n = j * 16 + l15;
                int cs = (k0 + g8) ^ SWZ(n);
                bb[j] = *(const bf16x8*)(lB + (size_t)n * LBP + cs);
            }
#pragma unroll
            for (int i = 0; i < 4; ++i)
#pragma unroll
                for (int j = 0; j < 4; ++j)
                    acc[i][j] = __builtin_amdgcn_mfma_f32_16x16x32_bf16(af[i], bb[j], acc[i][j], 0, 0, 0);
            __syncthreads();
        }
        const float* bias = g ? bvp : bfp;
#pragma unroll
        for (int i = 0; i < 4; ++i) {
            int cc = wave * 64 + i * 16 + rg * 4;     // channel within group 0..255
            int e = cc >> 5, d0 = cc & 31;
            float bi0 = bias[cc + 0], bi1 = bias[cc + 1];
            float bi2 = bias[cc + 2], bi3 = bias[cc + 3];
            ushort* dstb = fv + ((size_t)((b * 8 + e) * 2 + g) * NPIX) * 32 + d0;
#pragma unroll
            for (int j = 0; j < 4; ++j) {
                int n = n0 + j * 16 + l15;
                unsigned lo = (unsigned)f2b(acc[i][j][0] + bi0) | ((unsigned)f2b(acc[i][j][1] + bi1) << 16);
                unsigned hi = (unsigned)f2b(acc[i][j][2] + bi2) | ((unsigned)f2b(acc[i][j][3] + bi3) << 16);
                *(uint2*)(dstb + (size_t)n * 32) = make_uint2(lo, hi);
            }
        }
    }
}

// ---------------------------------------------------------------------------
// cluster_reduce: grid (9 chunks, 128 be). Partial sums + sg in-place + mapo.
// ---------------------------------------------------------------------------
__global__ __launch_bounds__(256, 2) void cluster_reduce(const ushort* __restrict__ fv,
                                                         const unsigned char* __restrict__ idxg,
                                                         float* __restrict__ zsg,
                                                         const float* __restrict__ beta_p,
                                                         float* __restrict__ partial,
                                                         float* __restrict__ mapo) {
    __shared__ float wred[4][136];
    int chunk = blockIdx.x, be = blockIdx.y;
    int t = threadIdx.x;
    float beta = beta_p[0];
    float acc[4][32] = {};
    float den[4] = {};
    const ushort* fb = fv + ((size_t)(be * 2) * NPIX) * 32;       // feat
    const ushort* vb = fv + ((size_t)(be * 2 + 1) * NPIX) * 32;   // value
    const unsigned char* ib = idxg + (size_t)be * NPIX;
    float* zb = zsg + (size_t)be * NPIX;
    int n0 = chunk * 1024;
#pragma unroll
    for (int p = 0; p < 4; ++p) {
        int n = n0 + p * 256 + t;
        const uint4* fq = (const uint4*)(fb + (size_t)n * 32);
        float f[32];
        unpack8(fq[0], f); unpack8(fq[1], f + 8); unpack8(fq[2], f + 16); unpack8(fq[3], f + 24);
        float nr = 0.f;
#pragma unroll
        for (int d = 0; d < 32; ++d) nr += f[d] * f[d];
        float inv = 1.f / fmaxf(sqrtf(nr), 1e-12f);
        float sg = 1.f / (1.f + __expf(-(beta + zb[n] * inv)));
        zb[n] = sg;
        int bm = ib[n];
        const uint4* vq = (const uint4*)(vb + (size_t)n * 32);
        float v[32];
        unpack8(vq[0], v); unpack8(vq[1], v + 8); unpack8(vq[2], v + 16); unpack8(vq[3], v + 24);
        int h = n / HH, w = n - h * HH;
        int mq = ((h >= 48) ? 2 : 0) + ((w >= 48) ? 1 : 0);
#pragma unroll
        for (int m = 0; m < 4; ++m) {
            float wm = ((bm == m) ? sg : 0.f) + ((mq == m) ? (1.f / 2304.f) : 0.f);
#pragma unroll
            for (int d = 0; d < 32; ++d) acc[m][d] = fmaf(wm, v[d], acc[m][d]);
            den[m] += (bm == m) ? sg : 0.f;
        }
        if (be == 0) mapo[n] = (float)bm;
    }

    int wave = t >> 6, lane = t & 63;
#pragma unroll
    for (int m = 0; m < 4; ++m) {
#pragma unroll
        for (int d = 0; d < 32; ++d) {
            float v_ = acc[m][d];
#pragma unroll
            for (int off = 32; off >= 1; off >>= 1) v_ += __shfl_xor(v_, off, 64);
            if (lane == 0) wred[wave][m * 32 + d] = v_;
        }
        float dv = den[m];
#pragma unroll
        for (int off = 32; off >= 1; off >>= 1) dv += __shfl_xor(dv, off, 64);
        if (lane == 0) wred[wave][128 + m] = dv;
    }
    __syncthreads();
    if (t < 132) {
        partial[((size_t)be * 9 + chunk) * 136 + t] =
            wred[0][t] + wred[1][t] + wred[2][t] + wred[3][t];
    }
}

// ---------------------------------------------------------------------------
// agg_pa: grid (16 b). agg from partials, then PAb[b][o][em] = bf16(Wp·agg)
// ---------------------------------------------------------------------------
__global__ __launch_bounds__(256) void agg_pa_kernel(const float* __restrict__ partial,
                                                     const float* __restrict__ Wp,
                                                     ushort* __restrict__ PAb) {
    __shared__ float aggs[8][4][32];
    __shared__ float tmp[136];
    int b = blockIdx.x;
    int t = threadIdx.x;
    for (int e = 0; e < 8; ++e) {
        int be = b * 8 + e;
        if (t < 132) {
            float s = 0.f;
#pragma unroll
            for (int c2 = 0; c2 < 9; ++c2) s += partial[((size_t)be * 9 + c2) * 136 + t];
            tmp[t] = s;
        }
        __syncthreads();
        if (t < 128) aggs[e][t >> 5][t & 31] = tmp[t] / (tmp[128 + (t >> 5)] + 1.0f);
        __syncthreads();
    }
    // thread t = output channel o
    const float* wrow = Wp + (size_t)t * 256;
    unsigned u[16];
#pragma unroll
    for (int k = 0; k < 16; ++k) {
        float s0 = 0.f, s1 = 0.f;
        int em0 = 2 * k, em1 = 2 * k + 1;
        int e0 = em0 >> 2, m0 = em0 & 3;
        int e1 = em1 >> 2, m1 = em1 & 3;
#pragma unroll
        for (int d = 0; d < 32; ++d) {
            s0 += wrow[e0 * 32 + d] * aggs[e0][m0][d];
            s1 += wrow[e1 * 32 + d] * aggs[e1][m1][d];
        }
        u[k] = (unsigned)f2b(s0) | ((unsigned)f2b(s1) << 16);
    }
    uint4* pab = (uint4*)(PAb + (size_t)b * 8192 + (size_t)t * 32);
    pab[0] = make_uint4(u[0], u[1], u[2], u[3]);
    pab[1] = make_uint4(u[4], u[5], u[6], u[7]);
    pab[2] = make_uint4(u[8], u[9], u[10], u[11]);
    pab[3] = make_uint4(u[12], u[13], u[14], u[15]);
}

// ---------------------------------------------------------------------------
// gemm_out: out[b][o][n] = bp[o] + PA(256x32)·W(32xn); W built in registers
// from sg/idx (one-hot). K=32 = one MFMA step; no LDS, no syncthreads.
// ---------------------------------------------------------------------------
__global__ __launch_bounds__(256) void gemm_out(const ushort* __restrict__ PAb,
                                                const float* __restrict__ sgv,
                                                const unsigned char* __restrict__ idxg,
                                                const float* __restrict__ bpp,
                                                float* __restrict__ out) {
    int nt = blockIdx.x, b = blockIdx.y;
    int t = threadIdx.x, wave = t >> 6, lane = t & 63;
    int wr = wave >> 1, wc = wave & 1;
    int l15 = lane & 15, kg = lane >> 4;
    const ushort* pab = PAb + (size_t)b * 8192;
    bf16x8 af[8];
#pragma unroll
    for (int i = 0; i < 8; ++i)
        af[i] = *(const bf16x8*)(pab + (size_t)(wr * 128 + i * 16 + l15) * 32 + kg * 8);
    int e0 = kg * 2;
    bf16x8 bb[4];
#pragma unroll
    for (int j = 0; j < 4; ++j) {
        int gn = nt * 128 + wc * 64 + j * 16 + l15;
        size_t ofs0 = ((size_t)(b * 8 + e0)) * NPIX + gn;
        float s0 = sgv[ofs0];
        float s1 = sgv[ofs0 + NPIX];
        int i0 = idxg[ofs0];
        int i1 = idxg[ofs0 + NPIX];
        unsigned h0 = f2b(s0), h1 = f2b(s1);
        unsigned w0 = (i0 & 1) ? (h0 << 16) : h0;
        unsigned w1 = (i1 & 1) ? (h1 << 16) : h1;
        uint4 q;
        q.x = (i0 >> 1) ? 0u : w0;
        q.y = (i0 >> 1) ? w0 : 0u;
        q.z = (i1 >> 1) ? 0u : w1;
        q.w = (i1 >> 1) ? w1 : 0u;
        bb[j] = __builtin_bit_cast(bf16x8, q);
    }
    f32x4 acc[8][4] = {};
#pragma unroll
    for (int i = 0; i < 8; ++i)
#pragma unroll
        for (int j = 0; j < 4; ++j)
            acc[i][j] = __builtin_amdgcn_mfma_f32_16x16x32_bf16(af[i], bb[j], acc[i][j], 0, 0, 0);
#pragma unroll
    for (int i = 0; i < 8; ++i) {
        int o0 = wr * 128 + i * 16 + kg * 4;
        float4 bi = *(const float4*)(bpp + o0);
#pragma unroll
        for (int j = 0; j < 4; ++j) {
            int gn = nt * 128 + wc * 64 + j * 16 + l15;
            size_t base = ((size_t)(b * 256 + o0)) * NPIX + gn;
            out[base] = acc[i][j][0] + bi.x;
            out[base + (size_t)NPIX] = acc[i][j][1] + bi.y;
            out[base + 2 * (size_t)NPIX] = acc[i][j][2] + bi.z;
            out[base + 3 * (size_t)NPIX] = acc[i][j][3] + bi.w;
        }
    }
}

// ---------------------------------------------------------------------------
extern "C" void kernel_launch(void* const* d_in, const int* in_sizes, int n_in,
                              void* d_out, int out_size, void* d_ws, size_t ws_size,
                              hipStream_t stream) {
    const float* x   = (const float*)d_in[0];
    const float* Wf  = (const float*)d_in[1];
    const float* bfp = (const float*)d_in[2];
    const float* Wv  = (const float*)d_in[3];
    const float* bvp = (const float*)d_in[4];
    const float* Wp  = (const float*)d_in[5];
    const float* bpp = (const float*)d_in[6];
    const float* al  = (const float*)d_in[7];
    const float* bt  = (const float*)d_in[8];
    const float* ce  = (const float*)d_in[9];
    float* out = (float*)d_out;

    // Workspace (bytes):
    char* ws = (char*)d_ws;
    ushort* wbuf = (ushort*)(ws + 75497472);                     //    262,144 B (Wf,Wv bf16)
    float*  GT   = (float*)(ws + 75759616);                      //     32,768 B
    float*  gb   = (float*)(ws + 75792384);                      //        256 B
    unsigned char* idxg = (unsigned char*)(ws + 75792640);       //  1,179,648 B
    float*  zbest = (float*)(ws + 76972288);                     //  4,718,592 B (->sg in-place)
    float*  partial = (float*)(ws + 81690880);                   //    626,688 B
    ushort* PAb   = (ushort*)(ws + 82317568);                    //    262,144 B -> 82,579,712 total

    // fv (bf16, 151MB) lives in d_out; fully consumed before gemm_out overwrites.
    ushort* fv = (ushort*)d_out;
    float* mapo = out + (size_t)BB * DD * NPIX;

    wprep_kernel<<<dim3(160), 256, 0, stream>>>(Wf, Wv, bfp, ce, wbuf, GT, gb);
    gmap_kernel<<<dim3(36, BB, 2), 256, 0, stream>>>(x, GT, gb, al, idxg, zbest);
    gemm_fvx<<<dim3(144, BB), 256, 0, stream>>>(wbuf, bfp, bvp, x, fv);
    cluster_reduce<<<dim3(9, 128), 256, 0, stream>>>(fv, idxg, zbest, bt, partial, mapo);
    agg_pa_kernel<<<dim3(BB), 256, 0, stream>>>(partial, Wp, PAb);
    gemm_out<<<dim3(72, BB), 256, 0, stream>>>(PAb, zbest, idxg, bpp, out);
}

// Round 18
// 273.630 us; speedup vs baseline: 1.0027x; 1.0027x over previous
//
#include <hip/hip_runtime.h>
#include <hip/hip_bf16.h>

#define BB 16
#define CIN 256
#define DD 256
#define HH 96
#define NPIX 9216
#define HEADS 8
#define HD 32
#define MM 4

typedef short bf16x8 __attribute__((ext_vector_type(8)));
typedef float f32x4 __attribute__((ext_vector_type(4)));

__device__ __forceinline__ float b2f(unsigned u) {
    unsigned x = u << 16;
    return __builtin_bit_cast(float, x);
}
__device__ __forceinline__ ushort f2b(float f) {
    unsigned x = __builtin_bit_cast(unsigned, f);
    unsigned r = (x + 0x7FFF + ((x >> 16) & 1)) >> 16;  // RNE
    return (ushort)r;
}
__device__ __forceinline__ void gload16(const ushort* g, ushort* l) {
    __builtin_amdgcn_global_load_lds(
        (const __attribute__((address_space(1))) unsigned int*)g,
        (__attribute__((address_space(3))) unsigned int*)l, 16, 0, 0);
}

// ---------------------------------------------------------------------------
// wprep: blocks 0..127: Wf,Wv f32 -> bf16 wb; blocks 128..159: GT + gb.
// ---------------------------------------------------------------------------
__global__ __launch_bounds__(256) void wprep_kernel(const float* __restrict__ Wf,
                                                    const float* __restrict__ Wv,
                                                    const float* __restrict__ bfp,
                                                    const float* __restrict__ centers,
                                                    ushort* __restrict__ wb,
                                                    float* __restrict__ GT,
                                                    float* __restrict__ gb) {
    __shared__ float cns[4][32];
    int t = threadIdx.x;
    if (blockIdx.x < 128) {
        int i = (blockIdx.x * 256 + t) * 4;
        float4 v;
        if (i < 65536) v = *(const float4*)(Wf + i);
        else v = *(const float4*)(Wv + (i - 65536));
        ushort4 o;
        o.x = f2b(v.x); o.y = f2b(v.y); o.z = f2b(v.z); o.w = f2b(v.w);
        *(ushort4*)(wb + i) = o;
        return;
    }
    if (t < 4) {
        float c[32]; float s = 0.f;
        for (int d = 0; d < 32; ++d) { c[d] = centers[t * 32 + d]; s += c[d] * c[d]; }
        float inv = 1.f / fmaxf(sqrtf(s), 1e-12f);
        for (int d = 0; d < 32; ++d) cns[t][d] = c[d] * inv;
    }
    __syncthreads();
    int i = (blockIdx.x - 128) * 256 + t;
    int c = i >> 5, em = i & 31;
    int e = em >> 2, m = em & 3;
    float s = 0.f;
#pragma unroll 8
    for (int d = 0; d < 32; ++d) s += cns[m][d] * Wf[(e * 32 + d) * 256 + c];
    GT[i] = s;
    if (blockIdx.x == 128 && t < 32) {
        int e2 = t >> 2, m2 = t & 3;
        float sb = 0.f;
        for (int d = 0; d < 32; ++d) sb += cns[m2][d] * bfp[e2 * 32 + d];
        gb[t] = sb;
    }
}

// ---------------------------------------------------------------------------
// gmap v5 + mapo: em split by blockIdx.z (uniform -> s_load). Grid (36,16,2).
// ---------------------------------------------------------------------------
__global__ __launch_bounds__(256) void gmap_kernel(const float* __restrict__ x,
                                                   const float* __restrict__ GT,
                                                   const float* __restrict__ gb,
                                                   const float* __restrict__ alpha_p,
                                                   unsigned char* __restrict__ idxg,
                                                   float* __restrict__ zbest,
                                                   float* __restrict__ mapo) {
    int b = blockIdx.y;
    int emh = blockIdx.z;                    // 0: em 0..15 (heads 0-3), 1: em 16..31
    int t = threadIdx.x;
    int n = blockIdx.x * 256 + t;
    float acc[16];
#pragma unroll
    for (int em = 0; em < 16; ++em) acc[em] = gb[emh * 16 + em];
    const float* xb = x + (size_t)b * CIN * NPIX + n;
    const float* gtb = GT + emh * 16;
#pragma unroll 8
    for (int c = 0; c < 256; ++c) {
        float xv = xb[(size_t)c * NPIX];
        const float* gr = gtb + c * 32;      // blockIdx-uniform -> s_load
#pragma unroll
        for (int em = 0; em < 16; ++em) acc[em] = fmaf(gr[em], xv, acc[em]);
    }
    float alpha = alpha_p[0];
#pragma unroll
    for (int h = 0; h < 4; ++h) {
        int e = emh * 4 + h;
        float z0 = alpha * acc[h * 4 + 0], z1 = alpha * acc[h * 4 + 1];
        float z2 = alpha * acc[h * 4 + 2], z3 = alpha * acc[h * 4 + 3];
        int bm = 0; float bz = z0;
        if (z1 > bz) { bz = z1; bm = 1; }
        if (z2 > bz) { bz = z2; bm = 2; }
        if (z3 > bz) { bz = z3; bm = 3; }
        size_t o = ((size_t)(b * 8 + e)) * NPIX + n;
        idxg[o] = (unsigned char)bm;
        zbest[o] = bz;
        if (b == 0 && emh == 0 && h == 0) mapo[n] = (float)bm;
    }
}

// ---------------------------------------------------------------------------
// gemm_fvc: fused convs + clustering. Block = 64 n x all 512 o (r16 core).
// Feat phase -> ||f||^2 via shfl over rg-lanes -> sg (in-place over zbest).
// Value phase -> wm-weighted partial sums via shfl over l15-lanes -> atomicAdd
// into partial[be][132] ([m*32+d]=sums, [128+m]=den). fv NEVER materialized.
// Grid (144, 16).
// ---------------------------------------------------------------------------
__global__ __launch_bounds__(256, 2) void gemm_fvc(const ushort* __restrict__ wb,
                                                   const float* __restrict__ bfp,
                                                   const float* __restrict__ bvp,
                                                   const float* __restrict__ x,
                                                   const unsigned char* __restrict__ idxg,
                                                   float* __restrict__ zsg,
                                                   const float* __restrict__ beta_p,
                                                   float* __restrict__ partial) {
    __shared__ ushort lB[64 * 256];   // 32 KB, swizzled
    __shared__ ushort lA[256 * 32];   // 16 KB
    int nt = blockIdx.x, b = blockIdx.y;
    int t = threadIdx.x;
    int wave = t >> 6, lane = t & 63;
    int l15 = lane & 15, g8 = (lane >> 4) * 8, rg = lane >> 4;
    int n0 = nt * 64;

    // ---- B-stage (r16): thread t: c-pairs c0 = s*64 + 2*(t&31), n-block (t>>5)*8
    {
        int cpl = 2 * (t & 31);
        int j0 = (t >> 5) * 8;
#pragma unroll
        for (int s = 0; s < 4; ++s) {
            int c0 = s * 64 + cpl;
            const float* xr = x + ((size_t)(b * CIN + c0)) * NPIX + n0 + j0;
            float4 u0 = *(const float4*)(xr);
            float4 u1 = *(const float4*)(xr + 4);
            float4 v0 = *(const float4*)(xr + NPIX);
            float4 v1 = *(const float4*)(xr + NPIX + 4);
            float a0[8] = {u0.x, u0.y, u0.z, u0.w, u1.x, u1.y, u1.z, u1.w};
            float a1[8] = {v0.x, v0.y, v0.z, v0.w, v1.x, v1.y, v1.z, v1.w};
#pragma unroll
            for (int i = 0; i < 8; ++i) {
                int n = j0 + i;
                int cs = c0 ^ ((n & 7) << 3);
                unsigned pk = (unsigned)f2b(a0[i]) | ((unsigned)f2b(a1[i]) << 16);
                *(unsigned*)(lB + (size_t)n * 256 + cs) = pk;
            }
        }
    }
    __syncthreads();

    float beta = beta_p[0];
    int mq[4];
#pragma unroll
    for (int j = 0; j < 4; ++j) {
        int n = n0 + j * 16 + l15;
        int hh = n / HH, ww = n - hh * HH;
        mq[j] = ((hh >= 48) ? 2 : 0) + ((ww >= 48) ? 1 : 0);
    }

    const ushort* aBase = wb + (t >> 2) * 256 + (t & 3) * 8;
    ushort* la0 = lA + wave * 512;    // HW adds lane*16B

    // ================= Phase g=0: feat =================
    f32x4 acc[4][4] = {};
    for (int kk = 0; kk < 8; ++kk) {
        int k0 = kk * 32;
        const ushort* aSrc = aBase;
        gload16(aSrc + k0, la0);
        gload16(aSrc + 64 * 256 + k0, la0 + 2048);
        gload16(aSrc + 128 * 256 + k0, la0 + 4096);
        gload16(aSrc + 192 * 256 + k0, la0 + 6144);
        __syncthreads();
        bf16x8 af[4], bb[4];
#pragma unroll
        for (int i = 0; i < 4; ++i)
            af[i] = *(const bf16x8*)(lA + (wave * 64 + i * 16 + l15) * 32 + g8);
#pragma unroll
        for (int j = 0; j < 4; ++j) {
            int n = j * 16 + l15;
            int cs = (k0 + g8) ^ ((n & 7) << 3);
            bb[j] = *(const bf16x8*)(lB + (size_t)n * 256 + cs);
        }
#pragma unroll
        for (int i = 0; i < 4; ++i)
#pragma unroll
            for (int j = 0; j < 4; ++j)
                acc[i][j] = __builtin_amdgcn_mfma_f32_16x16x32_bf16(af[i], bb[j], acc[i][j], 0, 0, 0);
        __syncthreads();
    }
    // + feat bias (f32, unrounded)
#pragma unroll
    for (int i = 0; i < 4; ++i) {
        int cc = wave * 64 + i * 16 + rg * 4;
        float q0 = bfp[cc], q1 = bfp[cc + 1], q2 = bfp[cc + 2], q3 = bfp[cc + 3];
#pragma unroll
        for (int j = 0; j < 4; ++j) {
            acc[i][j][0] += q0; acc[i][j][1] += q1; acc[i][j][2] += q2; acc[i][j][3] += q3;
        }
    }
    // norms -> sg; wm per (head, pixel, m)
    float sg[2][4]; int bmv[2][4]; float wm[2][4][4];
#pragma unroll
    for (int h = 0; h < 2; ++h) {
        int e = wave * 2 + h;
#pragma unroll
        for (int j = 0; j < 4; ++j) {
            float nr = 0.f;
#pragma unroll
            for (int i2 = 0; i2 < 2; ++i2) {
                int i = h * 2 + i2;
#pragma unroll
                for (int r = 0; r < 4; ++r) nr += acc[i][j][r] * acc[i][j][r];
            }
            nr += __shfl_xor(nr, 16);
            nr += __shfl_xor(nr, 32);   // full 32-d norm on all rg lanes
            size_t o = ((size_t)(b * 8 + e)) * NPIX + n0 + j * 16 + l15;
            float z = zsg[o];
            int bm = idxg[o];
            float inv = 1.f / fmaxf(sqrtf(nr), 1e-12f);
            float s = 1.f / (1.f + __expf(-(beta + z * inv)));
            sg[h][j] = s; bmv[h][j] = bm;
            if (rg == 0) zsg[o] = s;    // sg out, in-place (load above already done wave-wide)
#pragma unroll
            for (int m = 0; m < 4; ++m)
                wm[h][j][m] = ((bm == m) ? s : 0.f) + ((mq[j] == m) ? (1.f / 2304.f) : 0.f);
        }
    }

    // ================= Phase g=1: value =================
    f32x4 acc2[4][4] = {};
    for (int kk = 0; kk < 8; ++kk) {
        int k0 = kk * 32;
        const ushort* aSrc = aBase + 65536;
        gload16(aSrc + k0, la0);
        gload16(aSrc + 64 * 256 + k0, la0 + 2048);
        gload16(aSrc + 128 * 256 + k0, la0 + 4096);
        gload16(aSrc + 192 * 256 + k0, la0 + 6144);
        __syncthreads();
        bf16x8 af[4], bb[4];
#pragma unroll
        for (int i = 0; i < 4; ++i)
            af[i] = *(const bf16x8*)(lA + (wave * 64 + i * 16 + l15) * 32 + g8);
#pragma unroll
        for (int j = 0; j < 4; ++j) {
            int n = j * 16 + l15;
            int cs = (k0 + g8) ^ ((n & 7) << 3);
            bb[j] = *(const bf16x8*)(lB + (size_t)n * 256 + cs);
        }
#pragma unroll
        for (int i = 0; i < 4; ++i)
#pragma unroll
            for (int j = 0; j < 4; ++j)
                acc2[i][j] = __builtin_amdgcn_mfma_f32_16x16x32_bf16(af[i], bb[j], acc2[i][j], 0, 0, 0);
        __syncthreads();
    }
    // + value bias
#pragma unroll
    for (int i = 0; i < 4; ++i) {
        int cc = wave * 64 + i * 16 + rg * 4;
        float q0 = bvp[cc], q1 = bvp[cc + 1], q2 = bvp[cc + 2], q3 = bvp[cc + 3];
#pragma unroll
        for (int j = 0; j < 4; ++j) {
            acc2[i][j][0] += q0; acc2[i][j][1] += q1; acc2[i][j][2] += q2; acc2[i][j][3] += q3;
        }
    }
    // weighted partial sums -> atomics
#pragma unroll
    for (int h = 0; h < 2; ++h) {
        int e = wave * 2 + h;
        int beidx = b * 8 + e;
#pragma unroll
        for (int m = 0; m < 4; ++m) {
            float s = 0.f;
#pragma unroll
            for (int j = 0; j < 4; ++j) s += (bmv[h][j] == m) ? sg[h][j] : 0.f;
            s += __shfl_xor(s, 1); s += __shfl_xor(s, 2);
            s += __shfl_xor(s, 4); s += __shfl_xor(s, 8);
            if (lane == 0) atomicAdd(&partial[(size_t)beidx * 132 + 128 + m], s);
        }
#pragma unroll
        for (int i2 = 0; i2 < 2; ++i2) {
            int i = h * 2 + i2;
#pragma unroll
            for (int r = 0; r < 4; ++r) {
                int d = i2 * 16 + rg * 4 + r;
#pragma unroll
                for (int m = 0; m < 4; ++m) {
                    float s = wm[h][0][m] * acc2[i][0][r] + wm[h][1][m] * acc2[i][1][r]
                            + wm[h][2][m] * acc2[i][2][r] + wm[h][3][m] * acc2[i][3][r];
                    s += __shfl_xor(s, 1); s += __shfl_xor(s, 2);
                    s += __shfl_xor(s, 4); s += __shfl_xor(s, 8);
                    if (l15 == 0) atomicAdd(&partial[(size_t)beidx * 132 + m * 32 + d], s);
                }
            }
        }
    }
}

// ---------------------------------------------------------------------------
// agg_pa v2: grid (16 b). aggs from partial[be][132], PAb = bf16(Wp·agg).
// ---------------------------------------------------------------------------
__global__ __launch_bounds__(256) void agg_pa_kernel(const float* __restrict__ partial,
                                                     const float* __restrict__ Wp,
                                                     ushort* __restrict__ PAb) {
    __shared__ float aggs[8][4][32];
    __shared__ float tmp[136];
    int b = blockIdx.x;
    int t = threadIdx.x;
    for (int e = 0; e < 8; ++e) {
        int be = b * 8 + e;
        if (t < 132) tmp[t] = partial[(size_t)be * 132 + t];
        __syncthreads();
        if (t < 128) aggs[e][t >> 5][t & 31] = tmp[t] / (tmp[128 + (t >> 5)] + 1.0f);
        __syncthreads();
    }
    const float* wrow = Wp + (size_t)t * 256;
    unsigned u[16];
#pragma unroll
    for (int k = 0; k < 16; ++k) {
        float s0 = 0.f, s1 = 0.f;
        int em0 = 2 * k, em1 = 2 * k + 1;
        int e0 = em0 >> 2, m0 = em0 & 3;
        int e1 = em1 >> 2, m1 = em1 & 3;
#pragma unroll
        for (int d = 0; d < 32; ++d) {
            s0 += wrow[e0 * 32 + d] * aggs[e0][m0][d];
            s1 += wrow[e1 * 32 + d] * aggs[e1][m1][d];
        }
        u[k] = (unsigned)f2b(s0) | ((unsigned)f2b(s1) << 16);
    }
    uint4* pab = (uint4*)(PAb + (size_t)b * 8192 + (size_t)t * 32);
    pab[0] = make_uint4(u[0], u[1], u[2], u[3]);
    pab[1] = make_uint4(u[4], u[5], u[6], u[7]);
    pab[2] = make_uint4(u[8], u[9], u[10], u[11]);
    pab[3] = make_uint4(u[12], u[13], u[14], u[15]);
}

// ---------------------------------------------------------------------------
// gemm_out: out[b][o][n] = bp[o] + PA(256x32)·W(32xn); W built in registers.
// ---------------------------------------------------------------------------
__global__ __launch_bounds__(256) void gemm_out(const ushort* __restrict__ PAb,
                                                const float* __restrict__ sgv,
                                                const unsigned char* __restrict__ idxg,
                                                const float* __restrict__ bpp,
                                                float* __restrict__ out) {
    int nt = blockIdx.x, b = blockIdx.y;
    int t = threadIdx.x, wave = t >> 6, lane = t & 63;
    int wr = wave >> 1, wc = wave & 1;
    int l15 = lane & 15, kg = lane >> 4;
    const ushort* pab = PAb + (size_t)b * 8192;
    bf16x8 af[8];
#pragma unroll
    for (int i = 0; i < 8; ++i)
        af[i] = *(const bf16x8*)(pab + (size_t)(wr * 128 + i * 16 + l15) * 32 + kg * 8);
    int e0 = kg * 2;
    bf16x8 bb[4];
#pragma unroll
    for (int j = 0; j < 4; ++j) {
        int gn = nt * 128 + wc * 64 + j * 16 + l15;
        size_t ofs0 = ((size_t)(b * 8 + e0)) * NPIX + gn;
        float s0 = sgv[ofs0];
        float s1 = sgv[ofs0 + NPIX];
        int i0 = idxg[ofs0];
        int i1 = idxg[ofs0 + NPIX];
        unsigned h0 = f2b(s0), h1 = f2b(s1);
        unsigned w0 = (i0 & 1) ? (h0 << 16) : h0;
        unsigned w1 = (i1 & 1) ? (h1 << 16) : h1;
        uint4 q;
        q.x = (i0 >> 1) ? 0u : w0;
        q.y = (i0 >> 1) ? w0 : 0u;
        q.z = (i1 >> 1) ? 0u : w1;
        q.w = (i1 >> 1) ? w1 : 0u;
        bb[j] = __builtin_bit_cast(bf16x8, q);
    }
    f32x4 acc[8][4] = {};
#pragma unroll
    for (int i = 0; i < 8; ++i)
#pragma unroll
        for (int j = 0; j < 4; ++j)
            acc[i][j] = __builtin_amdgcn_mfma_f32_16x16x32_bf16(af[i], bb[j], acc[i][j], 0, 0, 0);
#pragma unroll
    for (int i = 0; i < 8; ++i) {
        int o0 = wr * 128 + i * 16 + kg * 4;
        float4 bi = *(const float4*)(bpp + o0);
#pragma unroll
        for (int j = 0; j < 4; ++j) {
            int gn = nt * 128 + wc * 64 + j * 16 + l15;
            size_t base = ((size_t)(b * 256 + o0)) * NPIX + gn;
            out[base] = acc[i][j][0] + bi.x;
            out[base + (size_t)NPIX] = acc[i][j][1] + bi.y;
            out[base + 2 * (size_t)NPIX] = acc[i][j][2] + bi.z;
            out[base + 3 * (size_t)NPIX] = acc[i][j][3] + bi.w;
        }
    }
}

// ---------------------------------------------------------------------------
extern "C" void kernel_launch(void* const* d_in, const int* in_sizes, int n_in,
                              void* d_out, int out_size, void* d_ws, size_t ws_size,
                              hipStream_t stream) {
    const float* x   = (const float*)d_in[0];
    const float* Wf  = (const float*)d_in[1];
    const float* bfp = (const float*)d_in[2];
    const float* Wv  = (const float*)d_in[3];
    const float* bvp = (const float*)d_in[4];
    const float* Wp  = (const float*)d_in[5];
    const float* bpp = (const float*)d_in[6];
    const float* al  = (const float*)d_in[7];
    const float* bt  = (const float*)d_in[8];
    const float* ce  = (const float*)d_in[9];
    float* out = (float*)d_out;

    // Workspace (bytes):
    char* ws = (char*)d_ws;
    ushort* wbuf = (ushort*)(ws + 75497472);                     //    262,144 B (Wf,Wv bf16)
    float*  GT   = (float*)(ws + 75759616);                      //     32,768 B
    float*  gb   = (float*)(ws + 75792384);                      //        256 B
    unsigned char* idxg = (unsigned char*)(ws + 75792640);       //  1,179,648 B
    float*  zbest = (float*)(ws + 76972288);                     //  4,718,592 B (->sg in-place)
    float*  partial = (float*)(ws + 81690880);                   //     67,584 B (atomic acc)
    ushort* PAb   = (ushort*)(ws + 82317568);                    //    262,144 B

    float* mapo = out + (size_t)BB * DD * NPIX;

    wprep_kernel<<<dim3(160), 256, 0, stream>>>(Wf, Wv, bfp, ce, wbuf, GT, gb);
    hipMemsetAsync(partial, 0, 128 * 132 * sizeof(float), stream);
    gmap_kernel<<<dim3(36, BB, 2), 256, 0, stream>>>(x, GT, gb, al, idxg, zbest, mapo);
    gemm_fvc<<<dim3(144, BB), 256, 0, stream>>>(wbuf, bfp, bvp, x, idxg, zbest, bt, partial);
    agg_pa_kernel<<<dim3(BB), 256, 0, stream>>>(partial, Wp, PAb);
    gemm_out<<<dim3(72, BB), 256, 0, stream>>>(PAb, zbest, idxg, bpp, out);
}

// Round 19
// 215.254 us; speedup vs baseline: 1.2746x; 1.2712x over previous
//
#include <hip/hip_runtime.h>
#include <hip/hip_bf16.h>

#define BB 16
#define CIN 256
#define DD 256
#define HH 96
#define NPIX 9216
#define HEADS 8
#define HD 32
#define MM 4
#define NT 144

typedef short bf16x8 __attribute__((ext_vector_type(8)));
typedef float f32x4 __attribute__((ext_vector_type(4)));

__device__ __forceinline__ float b2f(unsigned u) {
    unsigned x = u << 16;
    return __builtin_bit_cast(float, x);
}
__device__ __forceinline__ ushort f2b(float f) {
    unsigned x = __builtin_bit_cast(unsigned, f);
    unsigned r = (x + 0x7FFF + ((x >> 16) & 1)) >> 16;  // RNE
    return (ushort)r;
}
__device__ __forceinline__ void gload16(const ushort* g, ushort* l) {
    __builtin_amdgcn_global_load_lds(
        (const __attribute__((address_space(1))) unsigned int*)g,
        (__attribute__((address_space(3))) unsigned int*)l, 16, 0, 0);
}

// ---------------------------------------------------------------------------
// wprep: blocks 0..127: Wf,Wv f32 -> bf16 wb; blocks 128..159: GT + gb.
// ---------------------------------------------------------------------------
__global__ __launch_bounds__(256) void wprep_kernel(const float* __restrict__ Wf,
                                                    const float* __restrict__ Wv,
                                                    const float* __restrict__ bfp,
                                                    const float* __restrict__ centers,
                                                    ushort* __restrict__ wb,
                                                    float* __restrict__ GT,
                                                    float* __restrict__ gb) {
    __shared__ float cns[4][32];
    int t = threadIdx.x;
    if (blockIdx.x < 128) {
        int i = (blockIdx.x * 256 + t) * 4;
        float4 v;
        if (i < 65536) v = *(const float4*)(Wf + i);
        else v = *(const float4*)(Wv + (i - 65536));
        ushort4 o;
        o.x = f2b(v.x); o.y = f2b(v.y); o.z = f2b(v.z); o.w = f2b(v.w);
        *(ushort4*)(wb + i) = o;
        return;
    }
    if (t < 4) {
        float c[32]; float s = 0.f;
        for (int d = 0; d < 32; ++d) { c[d] = centers[t * 32 + d]; s += c[d] * c[d]; }
        float inv = 1.f / fmaxf(sqrtf(s), 1e-12f);
        for (int d = 0; d < 32; ++d) cns[t][d] = c[d] * inv;
    }
    __syncthreads();
    int i = (blockIdx.x - 128) * 256 + t;
    int c = i >> 5, em = i & 31;
    int e = em >> 2, m = em & 3;
    float s = 0.f;
#pragma unroll 8
    for (int d = 0; d < 32; ++d) s += cns[m][d] * Wf[(e * 32 + d) * 256 + c];
    GT[i] = s;
    if (blockIdx.x == 128 && t < 32) {
        int e2 = t >> 2, m2 = t & 3;
        float sb = 0.f;
        for (int d = 0; d < 32; ++d) sb += cns[m2][d] * bfp[e2 * 32 + d];
        gb[t] = sb;
    }
}

// ---------------------------------------------------------------------------
// gmap v5 + mapo: em split by blockIdx.z (uniform -> s_load). Grid (36,16,2).
// ---------------------------------------------------------------------------
__global__ __launch_bounds__(256) void gmap_kernel(const float* __restrict__ x,
                                                   const float* __restrict__ GT,
                                                   const float* __restrict__ gb,
                                                   const float* __restrict__ alpha_p,
                                                   unsigned char* __restrict__ idxg,
                                                   float* __restrict__ zbest,
                                                   float* __restrict__ mapo) {
    int b = blockIdx.y;
    int emh = blockIdx.z;                    // 0: em 0..15 (heads 0-3), 1: em 16..31
    int t = threadIdx.x;
    int n = blockIdx.x * 256 + t;
    float acc[16];
#pragma unroll
    for (int em = 0; em < 16; ++em) acc[em] = gb[emh * 16 + em];
    const float* xb = x + (size_t)b * CIN * NPIX + n;
    const float* gtb = GT + emh * 16;
#pragma unroll 8
    for (int c = 0; c < 256; ++c) {
        float xv = xb[(size_t)c * NPIX];
        const float* gr = gtb + c * 32;      // blockIdx-uniform -> s_load
#pragma unroll
        for (int em = 0; em < 16; ++em) acc[em] = fmaf(gr[em], xv, acc[em]);
    }
    float alpha = alpha_p[0];
#pragma unroll
    for (int h = 0; h < 4; ++h) {
        int e = emh * 4 + h;
        float z0 = alpha * acc[h * 4 + 0], z1 = alpha * acc[h * 4 + 1];
        float z2 = alpha * acc[h * 4 + 2], z3 = alpha * acc[h * 4 + 3];
        int bm = 0; float bz = z0;
        if (z1 > bz) { bz = z1; bm = 1; }
        if (z2 > bz) { bz = z2; bm = 2; }
        if (z3 > bz) { bz = z3; bm = 3; }
        size_t o = ((size_t)(b * 8 + e)) * NPIX + n;
        idxg[o] = (unsigned char)bm;
        zbest[o] = bz;
        if (b == 0 && emh == 0 && h == 0) mapo[n] = (float)bm;
    }
}

// ---------------------------------------------------------------------------
// gemm_fvc v2: fused convs + clustering, NO atomics. Per-block partial sums
// written fire-and-forget to partial2[be][132][NT] (each slot written by
// exactly one lane of one block -> no memset, no contention).
// Grid (144, 16).
// ---------------------------------------------------------------------------
__global__ __launch_bounds__(256, 2) void gemm_fvc(const ushort* __restrict__ wb,
                                                   const float* __restrict__ bfp,
                                                   const float* __restrict__ bvp,
                                                   const float* __restrict__ x,
                                                   const unsigned char* __restrict__ idxg,
                                                   float* __restrict__ zsg,
                                                   const float* __restrict__ beta_p,
                                                   float* __restrict__ partial2) {
    __shared__ ushort lB[64 * 256];   // 32 KB, swizzled
    __shared__ ushort lA[256 * 32];   // 16 KB
    int nt = blockIdx.x, b = blockIdx.y;
    int t = threadIdx.x;
    int wave = t >> 6, lane = t & 63;
    int l15 = lane & 15, g8 = (lane >> 4) * 8, rg = lane >> 4;
    int n0 = nt * 64;

    // ---- B-stage (r16): thread t: c-pairs c0 = s*64 + 2*(t&31), n-block (t>>5)*8
    {
        int cpl = 2 * (t & 31);
        int j0 = (t >> 5) * 8;
#pragma unroll
        for (int s = 0; s < 4; ++s) {
            int c0 = s * 64 + cpl;
            const float* xr = x + ((size_t)(b * CIN + c0)) * NPIX + n0 + j0;
            float4 u0 = *(const float4*)(xr);
            float4 u1 = *(const float4*)(xr + 4);
            float4 v0 = *(const float4*)(xr + NPIX);
            float4 v1 = *(const float4*)(xr + NPIX + 4);
            float a0[8] = {u0.x, u0.y, u0.z, u0.w, u1.x, u1.y, u1.z, u1.w};
            float a1[8] = {v0.x, v0.y, v0.z, v0.w, v1.x, v1.y, v1.z, v1.w};
#pragma unroll
            for (int i = 0; i < 8; ++i) {
                int n = j0 + i;
                int cs = c0 ^ ((n & 7) << 3);
                unsigned pk = (unsigned)f2b(a0[i]) | ((unsigned)f2b(a1[i]) << 16);
                *(unsigned*)(lB + (size_t)n * 256 + cs) = pk;
            }
        }
    }
    __syncthreads();

    float beta = beta_p[0];
    int mq[4];
#pragma unroll
    for (int j = 0; j < 4; ++j) {
        int n = n0 + j * 16 + l15;
        int hh = n / HH, ww = n - hh * HH;
        mq[j] = ((hh >= 48) ? 2 : 0) + ((ww >= 48) ? 1 : 0);
    }

    const ushort* aBase = wb + (t >> 2) * 256 + (t & 3) * 8;
    ushort* la0 = lA + wave * 512;    // HW adds lane*16B

    // ================= Phase g=0: feat =================
    f32x4 acc[4][4] = {};
    for (int kk = 0; kk < 8; ++kk) {
        int k0 = kk * 32;
        const ushort* aSrc = aBase;
        gload16(aSrc + k0, la0);
        gload16(aSrc + 64 * 256 + k0, la0 + 2048);
        gload16(aSrc + 128 * 256 + k0, la0 + 4096);
        gload16(aSrc + 192 * 256 + k0, la0 + 6144);
        __syncthreads();
        bf16x8 af[4], bb[4];
#pragma unroll
        for (int i = 0; i < 4; ++i)
            af[i] = *(const bf16x8*)(lA + (wave * 64 + i * 16 + l15) * 32 + g8);
#pragma unroll
        for (int j = 0; j < 4; ++j) {
            int n = j * 16 + l15;
            int cs = (k0 + g8) ^ ((n & 7) << 3);
            bb[j] = *(const bf16x8*)(lB + (size_t)n * 256 + cs);
        }
#pragma unroll
        for (int i = 0; i < 4; ++i)
#pragma unroll
            for (int j = 0; j < 4; ++j)
                acc[i][j] = __builtin_amdgcn_mfma_f32_16x16x32_bf16(af[i], bb[j], acc[i][j], 0, 0, 0);
        __syncthreads();
    }
    // + feat bias (f32, unrounded)
#pragma unroll
    for (int i = 0; i < 4; ++i) {
        int cc = wave * 64 + i * 16 + rg * 4;
        float q0 = bfp[cc], q1 = bfp[cc + 1], q2 = bfp[cc + 2], q3 = bfp[cc + 3];
#pragma unroll
        for (int j = 0; j < 4; ++j) {
            acc[i][j][0] += q0; acc[i][j][1] += q1; acc[i][j][2] += q2; acc[i][j][3] += q3;
        }
    }
    // norms -> sg; wm per (head, pixel, m)
    float sg[2][4]; int bmv[2][4]; float wm[2][4][4];
#pragma unroll
    for (int h = 0; h < 2; ++h) {
        int e = wave * 2 + h;
#pragma unroll
        for (int j = 0; j < 4; ++j) {
            float nr = 0.f;
#pragma unroll
            for (int i2 = 0; i2 < 2; ++i2) {
                int i = h * 2 + i2;
#pragma unroll
                for (int r = 0; r < 4; ++r) nr += acc[i][j][r] * acc[i][j][r];
            }
            nr += __shfl_xor(nr, 16);
            nr += __shfl_xor(nr, 32);   // full 32-d norm on all rg lanes
            size_t o = ((size_t)(b * 8 + e)) * NPIX + n0 + j * 16 + l15;
            float z = zsg[o];
            int bm = idxg[o];
            float inv = 1.f / fmaxf(sqrtf(nr), 1e-12f);
            float s = 1.f / (1.f + __expf(-(beta + z * inv)));
            sg[h][j] = s; bmv[h][j] = bm;
            if (rg == 0) zsg[o] = s;    // sg out, in-place
#pragma unroll
            for (int m = 0; m < 4; ++m)
                wm[h][j][m] = ((bm == m) ? s : 0.f) + ((mq[j] == m) ? (1.f / 2304.f) : 0.f);
        }
    }

    // ================= Phase g=1: value =================
    f32x4 acc2[4][4] = {};
    for (int kk = 0; kk < 8; ++kk) {
        int k0 = kk * 32;
        const ushort* aSrc = aBase + 65536;
        gload16(aSrc + k0, la0);
        gload16(aSrc + 64 * 256 + k0, la0 + 2048);
        gload16(aSrc + 128 * 256 + k0, la0 + 4096);
        gload16(aSrc + 192 * 256 + k0, la0 + 6144);
        __syncthreads();
        bf16x8 af[4], bb[4];
#pragma unroll
        for (int i = 0; i < 4; ++i)
            af[i] = *(const bf16x8*)(lA + (wave * 64 + i * 16 + l15) * 32 + g8);
#pragma unroll
        for (int j = 0; j < 4; ++j) {
            int n = j * 16 + l15;
            int cs = (k0 + g8) ^ ((n & 7) << 3);
            bb[j] = *(const bf16x8*)(lB + (size_t)n * 256 + cs);
        }
#pragma unroll
        for (int i = 0; i < 4; ++i)
#pragma unroll
            for (int j = 0; j < 4; ++j)
                acc2[i][j] = __builtin_amdgcn_mfma_f32_16x16x32_bf16(af[i], bb[j], acc2[i][j], 0, 0, 0);
        __syncthreads();
    }
    // + value bias
#pragma unroll
    for (int i = 0; i < 4; ++i) {
        int cc = wave * 64 + i * 16 + rg * 4;
        float q0 = bvp[cc], q1 = bvp[cc + 1], q2 = bvp[cc + 2], q3 = bvp[cc + 3];
#pragma unroll
        for (int j = 0; j < 4; ++j) {
            acc2[i][j][0] += q0; acc2[i][j][1] += q1; acc2[i][j][2] += q2; acc2[i][j][3] += q3;
        }
    }
    // weighted partial sums -> fire-and-forget per-block stores
#pragma unroll
    for (int h = 0; h < 2; ++h) {
        int e = wave * 2 + h;
        size_t pbase = (size_t)(b * 8 + e) * 132;
#pragma unroll
        for (int m = 0; m < 4; ++m) {
            float s = 0.f;
#pragma unroll
            for (int j = 0; j < 4; ++j) s += (bmv[h][j] == m) ? sg[h][j] : 0.f;
            s += __shfl_xor(s, 1); s += __shfl_xor(s, 2);
            s += __shfl_xor(s, 4); s += __shfl_xor(s, 8);
            if (lane == 0) partial2[(pbase + 128 + m) * NT + nt] = s;
        }
#pragma unroll
        for (int i2 = 0; i2 < 2; ++i2) {
            int i = h * 2 + i2;
#pragma unroll
            for (int r = 0; r < 4; ++r) {
                int d = i2 * 16 + rg * 4 + r;
#pragma unroll
                for (int m = 0; m < 4; ++m) {
                    float s = wm[h][0][m] * acc2[i][0][r] + wm[h][1][m] * acc2[i][1][r]
                            + wm[h][2][m] * acc2[i][2][r] + wm[h][3][m] * acc2[i][3][r];
                    s += __shfl_xor(s, 1); s += __shfl_xor(s, 2);
                    s += __shfl_xor(s, 4); s += __shfl_xor(s, 8);
                    if (l15 == 0) partial2[(pbase + m * 32 + d) * NT + nt] = s;
                }
            }
        }
    }
}

// ---------------------------------------------------------------------------
// agg_pa v3: grid (16 b). Sum partial2[be][132][NT] rows (coalesced float4),
// then PAb = bf16(Wp·agg).
// ---------------------------------------------------------------------------
__global__ __launch_bounds__(256) void agg_pa_kernel(const float* __restrict__ partial2,
                                                     const float* __restrict__ Wp,
                                                     ushort* __restrict__ PAb) {
    __shared__ float aggs[8][4][32];
    __shared__ float tmp[136];
    int b = blockIdx.x;
    int t = threadIdx.x;
    for (int e = 0; e < 8; ++e) {
        int be = b * 8 + e;
        if (t < 132) {
            const float* p = partial2 + ((size_t)be * 132 + t) * NT;
            float s = 0.f;
#pragma unroll
            for (int k = 0; k < NT; k += 4) {
                float4 v = *(const float4*)(p + k);
                s += v.x + v.y + v.z + v.w;
            }
            tmp[t] = s;
        }
        __syncthreads();
        if (t < 128) aggs[e][t >> 5][t & 31] = tmp[t] / (tmp[128 + (t >> 5)] + 1.0f);
        __syncthreads();
    }
    const float* wrow = Wp + (size_t)t * 256;
    unsigned u[16];
#pragma unroll
    for (int k = 0; k < 16; ++k) {
        float s0 = 0.f, s1 = 0.f;
        int em0 = 2 * k, em1 = 2 * k + 1;
        int e0 = em0 >> 2, m0 = em0 & 3;
        int e1 = em1 >> 2, m1 = em1 & 3;
#pragma unroll
        for (int d = 0; d < 32; ++d) {
            s0 += wrow[e0 * 32 + d] * aggs[e0][m0][d];
            s1 += wrow[e1 * 32 + d] * aggs[e1][m1][d];
        }
        u[k] = (unsigned)f2b(s0) | ((unsigned)f2b(s1) << 16);
    }
    uint4* pab = (uint4*)(PAb + (size_t)b * 8192 + (size_t)t * 32);
    pab[0] = make_uint4(u[0], u[1], u[2], u[3]);
    pab[1] = make_uint4(u[4], u[5], u[6], u[7]);
    pab[2] = make_uint4(u[8], u[9], u[10], u[11]);
    pab[3] = make_uint4(u[12], u[13], u[14], u[15]);
}

// ---------------------------------------------------------------------------
// gemm_out: out[b][o][n] = bp[o] + PA(256x32)·W(32xn); W built in registers.
// ---------------------------------------------------------------------------
__global__ __launch_bounds__(256) void gemm_out(const ushort* __restrict__ PAb,
                                                const float* __restrict__ sgv,
                                                const unsigned char* __restrict__ idxg,
                                                const float* __restrict__ bpp,
                                                float* __restrict__ out) {
    int nt = blockIdx.x, b = blockIdx.y;
    int t = threadIdx.x, wave = t >> 6, lane = t & 63;
    int wr = wave >> 1, wc = wave & 1;
    int l15 = lane & 15, kg = lane >> 4;
    const ushort* pab = PAb + (size_t)b * 8192;
    bf16x8 af[8];
#pragma unroll
    for (int i = 0; i < 8; ++i)
        af[i] = *(const bf16x8*)(pab + (size_t)(wr * 128 + i * 16 + l15) * 32 + kg * 8);
    int e0 = kg * 2;
    bf16x8 bb[4];
#pragma unroll
    for (int j = 0; j < 4; ++j) {
        int gn = nt * 128 + wc * 64 + j * 16 + l15;
        size_t ofs0 = ((size_t)(b * 8 + e0)) * NPIX + gn;
        float s0 = sgv[ofs0];
        float s1 = sgv[ofs0 + NPIX];
        int i0 = idxg[ofs0];
        int i1 = idxg[ofs0 + NPIX];
        unsigned h0 = f2b(s0), h1 = f2b(s1);
        unsigned w0 = (i0 & 1) ? (h0 << 16) : h0;
        unsigned w1 = (i1 & 1) ? (h1 << 16) : h1;
        uint4 q;
        q.x = (i0 >> 1) ? 0u : w0;
        q.y = (i0 >> 1) ? w0 : 0u;
        q.z = (i1 >> 1) ? 0u : w1;
        q.w = (i1 >> 1) ? w1 : 0u;
        bb[j] = __builtin_bit_cast(bf16x8, q);
    }
    f32x4 acc[8][4] = {};
#pragma unroll
    for (int i = 0; i < 8; ++i)
#pragma unroll
        for (int j = 0; j < 4; ++j)
            acc[i][j] = __builtin_amdgcn_mfma_f32_16x16x32_bf16(af[i], bb[j], acc[i][j], 0, 0, 0);
#pragma unroll
    for (int i = 0; i < 8; ++i) {
        int o0 = wr * 128 + i * 16 + kg * 4;
        float4 bi = *(const float4*)(bpp + o0);
#pragma unroll
        for (int j = 0; j < 4; ++j) {
            int gn = nt * 128 + wc * 64 + j * 16 + l15;
            size_t base = ((size_t)(b * 256 + o0)) * NPIX + gn;
            out[base] = acc[i][j][0] + bi.x;
            out[base + (size_t)NPIX] = acc[i][j][1] + bi.y;
            out[base + 2 * (size_t)NPIX] = acc[i][j][2] + bi.z;
            out[base + 3 * (size_t)NPIX] = acc[i][j][3] + bi.w;
        }
    }
}

// ---------------------------------------------------------------------------
extern "C" void kernel_launch(void* const* d_in, const int* in_sizes, int n_in,
                              void* d_out, int out_size, void* d_ws, size_t ws_size,
                              hipStream_t stream) {
    const float* x   = (const float*)d_in[0];
    const float* Wf  = (const float*)d_in[1];
    const float* bfp = (const float*)d_in[2];
    const float* Wv  = (const float*)d_in[3];
    const float* bvp = (const float*)d_in[4];
    const float* Wp  = (const float*)d_in[5];
    const float* bpp = (const float*)d_in[6];
    const float* al  = (const float*)d_in[7];
    const float* bt  = (const float*)d_in[8];
    const float* ce  = (const float*)d_in[9];
    float* out = (float*)d_out;

    // Workspace (bytes):
    char* ws = (char*)d_ws;
    float*  partial2 = (float*)ws;                               //  9,732,096 B (per-block partials, xT region)
    ushort* wbuf = (ushort*)(ws + 75497472);                     //    262,144 B (Wf,Wv bf16)
    float*  GT   = (float*)(ws + 75759616);                      //     32,768 B
    float*  gb   = (float*)(ws + 75792384);                      //        256 B
    unsigned char* idxg = (unsigned char*)(ws + 75792640);       //  1,179,648 B
    float*  zbest = (float*)(ws + 76972288);                     //  4,718,592 B (->sg in-place)
    ushort* PAb   = (ushort*)(ws + 82317568);                    //    262,144 B

    float* mapo = out + (size_t)BB * DD * NPIX;

    wprep_kernel<<<dim3(160), 256, 0, stream>>>(Wf, Wv, bfp, ce, wbuf, GT, gb);
    gmap_kernel<<<dim3(36, BB, 2), 256, 0, stream>>>(x, GT, gb, al, idxg, zbest, mapo);
    gemm_fvc<<<dim3(NT, BB), 256, 0, stream>>>(wbuf, bfp, bvp, x, idxg, zbest, bt, partial2);
    agg_pa_kernel<<<dim3(BB), 256, 0, stream>>>(partial2, Wp, PAb);
    gemm_out<<<dim3(72, BB), 256, 0, stream>>>(PAb, zbest, idxg, bpp, out);
}